// Round 19
// baseline (224.017 us; speedup 1.0000x reference)
//
#include <hip/hip_runtime.h>
#include <stdint.h>
#include <math.h>

#define T_SEQ 4096

typedef __attribute__((ext_vector_type(8))) short short8;
typedef __attribute__((ext_vector_type(4))) float f32x4;
typedef __attribute__((ext_vector_type(16))) float f32x16;
typedef __attribute__((ext_vector_type(4))) uint16_t u16x4;

__device__ __forceinline__ uint16_t f2bf(float f) {
  uint32_t u = __float_as_uint(f);
  u += 0x7FFFu + ((u >> 16) & 1u);
  return (uint16_t)(u >> 16);
}

// async global->LDS, 16B per lane; LDS dest is wave-uniform base + lane*16
__device__ __forceinline__ void gload_lds16(const uint16_t* g, uint16_t* l) {
  __builtin_amdgcn_global_load_lds(
      (const __attribute__((address_space(1))) void*)g,
      (__attribute__((address_space(3))) void*)l, 16, 0, 0);
}

// ---------------- convert x: f32 -> bf16 ----------------
__global__ void __launch_bounds__(256) k_cvt(const float* __restrict__ in,
                                             uint16_t* __restrict__ out, int n4) {
  int i = blockIdx.x * 256 + threadIdx.x;
  if (i >= n4) return;
  float4 v = reinterpret_cast<const float4*>(in)[i];
  u16x4 o = { f2bf(v.x), f2bf(v.y), f2bf(v.z), f2bf(v.w) };
  reinterpret_cast<u16x4*>(out)[i] = o;
}

// ------------- transpose+convert: w (RxC f32) -> wt (CxR bf16) -------------
__global__ void __launch_bounds__(256) k_tc(const float* __restrict__ w,
                                            uint16_t* __restrict__ wt, int R, int C) {
  __shared__ uint16_t tile[32][33];
  int tx = threadIdx.x & 31, ty = threadIdx.x >> 5;
  int r0 = blockIdx.y * 32, c0 = blockIdx.x * 32;
#pragma unroll
  for (int i = 0; i < 4; i++)
    tile[ty + 8 * i][tx] = f2bf(w[(size_t)(r0 + ty + 8 * i) * C + c0 + tx]);
  __syncthreads();
#pragma unroll
  for (int i = 0; i < 4; i++)
    wt[(size_t)(c0 + ty + 8 * i) * R + r0 + tx] = tile[tx][ty + 8 * i];
}

// -------- transpose V out of qkv: vT[bh*64+d][t] (t local to batch) --------
__global__ void __launch_bounds__(256) k_vt(const uint16_t* __restrict__ qkv,
                                            uint16_t* __restrict__ vT) {
  __shared__ uint16_t tile[64][65];
  const int bh = blockIdx.y, b = bh >> 4, h = bh & 15;
  const int t0 = blockIdx.x * 64;
  const int tid = threadIdx.x;
  const int r = tid >> 3, c8 = tid & 7;
  const uint16_t* src = qkv + ((size_t)b * T_SEQ + t0) * 3072 + h * 192 + 128;
#pragma unroll
  for (int i = 0; i < 2; i++) {
    int row = r + 32 * i;
    short8 v = *reinterpret_cast<const short8*>(src + (size_t)row * 3072 + c8 * 8);
#pragma unroll
    for (int j = 0; j < 8; j++) tile[row][c8 * 8 + j] = (uint16_t)v[j];
  }
  __syncthreads();
  uint16_t* dst = vT + ((size_t)bh * 64) * T_SEQ + t0;
#pragma unroll
  for (int i = 0; i < 2; i++) {
    int d = r + 32 * i;
    short8 v;
#pragma unroll
    for (int j = 0; j < 8; j++) v[j] = (short)tile[c8 * 8 + j][d];
    *reinterpret_cast<short8*>(dst + (size_t)d * T_SEQ + c8 * 8) = v;
  }
}

// ---- GEMM1 256x256, 8 waves (2x4), per-wave 128x64, BK=64, dbuf, phase-split ----
// (verified round 18, +7us vs 128^2) LDS 128KB (1 block/CU). Phys chunk = logical ^
// row&7; staging source chunk (l&7)^(l>>3). Tile t+1: A staged phase 0, B phase 1.
__global__ void __launch_bounds__(512, 1) k_gemm256p(const uint16_t* __restrict__ A,
                                                     const uint16_t* __restrict__ BT,
                                                     const float* __restrict__ bias,
                                                     uint16_t* __restrict__ Cout,
                                                     int M, int N, int K) {
  __shared__ __align__(16) uint16_t As[2][256 * 64];
  __shared__ __align__(16) uint16_t Bs[2][256 * 64];
  const int tid = threadIdx.x;
  const int lane = tid & 63, wid = tid >> 6;   // 8 waves
  const int lr = lane & 15, lg = lane >> 4;
  const int wr = wid >> 2, wc = wid & 3;       // 2 x 4 wave grid

  const int bid = blockIdx.x;
  const int cpx = gridDim.x >> 3;
  const int lin = (bid & 7) * cpx + (bid >> 3);
  const int mt = M >> 8;
  const int n0 = (lin / mt) * 256;
  const int m0 = (lin % mt) * 256;

  const f32x4 vzero = {0.f, 0.f, 0.f, 0.f};
  f32x4 acc[8][4];
#pragma unroll
  for (int i = 0; i < 8; i++)
#pragma unroll
    for (int j = 0; j < 4; j++) acc[i][j] = vzero;

  const int sl = lane >> 3, ss = lane & 7;
  const int swzs = (ss ^ sl) * 8;              // pre-swizzled source chunk
  const uint16_t* a0 = A + (size_t)(m0 + wid * 32 + sl) * K + swzs;
  const uint16_t* b0 = BT + (size_t)(n0 + wid * 32 + sl) * K + swzs;
  const size_t r8 = (size_t)8 * K;

#define STAGE_A(bsel, t)                                                  \
  do {                                                                    \
    const int ko_ = (t) * 64;                                             \
    gload_lds16(a0 + ko_,          &As[bsel][(wid * 32 + 0) * 64]);       \
    gload_lds16(a0 + r8 + ko_,     &As[bsel][(wid * 32 + 8) * 64]);       \
    gload_lds16(a0 + 2 * r8 + ko_, &As[bsel][(wid * 32 + 16) * 64]);      \
    gload_lds16(a0 + 3 * r8 + ko_, &As[bsel][(wid * 32 + 24) * 64]);      \
  } while (0)
#define STAGE_B(bsel, t)                                                  \
  do {                                                                    \
    const int ko_ = (t) * 64;                                             \
    gload_lds16(b0 + ko_,          &Bs[bsel][(wid * 32 + 0) * 64]);       \
    gload_lds16(b0 + r8 + ko_,     &Bs[bsel][(wid * 32 + 8) * 64]);       \
    gload_lds16(b0 + 2 * r8 + ko_, &Bs[bsel][(wid * 32 + 16) * 64]);      \
    gload_lds16(b0 + 3 * r8 + ko_, &Bs[bsel][(wid * 32 + 24) * 64]);      \
  } while (0)

  const int nt = K >> 6;   // 16
  const int fsw = lr & 7;
  STAGE_A(0, 0);
  STAGE_B(0, 0);
  __syncthreads();  // drains prologue loads

  for (int t = 0; t < nt; ++t) {
    const int cur = t & 1;
    const int nxt = cur ^ 1;

    short8 bf[4][2];
#pragma unroll
    for (int nj = 0; nj < 4; ++nj)
#pragma unroll
      for (int ks = 0; ks < 2; ++ks)
        bf[nj][ks] = *reinterpret_cast<const short8*>(
            &Bs[cur][(wc * 64 + nj * 16 + lr) * 64 + (((ks * 4 + lg) ^ fsw) * 8)]);

#define PHASE(mi0)                                                            \
  do {                                                                        \
    short8 af0k0 = *reinterpret_cast<const short8*>(                          \
        &As[cur][(wr * 128 + (mi0) * 16 + lr) * 64 + (((0 * 4 + lg) ^ fsw) * 8)]); \
    short8 af0k1 = *reinterpret_cast<const short8*>(                          \
        &As[cur][(wr * 128 + (mi0) * 16 + lr) * 64 + (((1 * 4 + lg) ^ fsw) * 8)]); \
    short8 af1k0 = *reinterpret_cast<const short8*>(                          \
        &As[cur][(wr * 128 + (mi0 + 1) * 16 + lr) * 64 + (((0 * 4 + lg) ^ fsw) * 8)]); \
    short8 af1k1 = *reinterpret_cast<const short8*>(                          \
        &As[cur][(wr * 128 + (mi0 + 1) * 16 + lr) * 64 + (((1 * 4 + lg) ^ fsw) * 8)]); \
    __builtin_amdgcn_s_setprio(1);                                            \
    _Pragma("unroll")                                                         \
    for (int nj = 0; nj < 4; ++nj) {                                          \
      acc[mi0][nj] = __builtin_amdgcn_mfma_f32_16x16x32_bf16(af0k0, bf[nj][0], acc[mi0][nj], 0, 0, 0); \
      acc[mi0][nj] = __builtin_amdgcn_mfma_f32_16x16x32_bf16(af0k1, bf[nj][1], acc[mi0][nj], 0, 0, 0); \
      acc[mi0 + 1][nj] = __builtin_amdgcn_mfma_f32_16x16x32_bf16(af1k0, bf[nj][0], acc[mi0 + 1][nj], 0, 0, 0); \
      acc[mi0 + 1][nj] = __builtin_amdgcn_mfma_f32_16x16x32_bf16(af1k1, bf[nj][1], acc[mi0 + 1][nj], 0, 0, 0); \
    }                                                                         \
    __builtin_amdgcn_s_setprio(0);                                            \
  } while (0)

    if (t + 1 < nt) STAGE_A(nxt, t + 1);
    PHASE(0);
    if (t + 1 < nt) STAGE_B(nxt, t + 1);
    PHASE(2);
    PHASE(4);
    PHASE(6);
#undef PHASE

    __syncthreads();
  }
#undef STAGE_A
#undef STAGE_B

#pragma unroll
  for (int nj = 0; nj < 4; nj++) {
    int col = n0 + wc * 64 + nj * 16 + lr;
    float bv = bias[col];
#pragma unroll
    for (int mi = 0; mi < 8; mi++) {
      int rowb = m0 + wr * 128 + mi * 16 + lg * 4;
#pragma unroll
      for (int r = 0; r < 4; r++)
        Cout[(size_t)(rowb + r) * N + col] = f2bf(acc[mi][nj][r] + bv);
    }
  }
}

// ---- GEMM2 256x128, 8 waves (2x4), per-wave 128x32, BK=64, dbuf, phase-split ----
// fp32 out. Same template as k_gemm256p with BN=128: B staged 16 rows/wave (2 gloads),
// LDS 96KB, grid 256 blocks = exactly 1.0 dispatch round (no tail).
__global__ void __launch_bounds__(512, 1) k_gemm2(const uint16_t* __restrict__ A,
                                                  const uint16_t* __restrict__ BT,
                                                  const float* __restrict__ bias,
                                                  float* __restrict__ Cout,
                                                  int M, int N, int K) {
  __shared__ __align__(16) uint16_t As[2][256 * 64];
  __shared__ __align__(16) uint16_t Bs[2][128 * 64];
  const int tid = threadIdx.x;
  const int lane = tid & 63, wid = tid >> 6;   // 8 waves
  const int lr = lane & 15, lg = lane >> 4;
  const int wr = wid >> 2, wc = wid & 3;       // 2 x 4 wave grid; wave tile 128x32

  const int bid = blockIdx.x;
  const int cpx = gridDim.x >> 3;
  const int lin = (bid & 7) * cpx + (bid >> 3);
  const int mt = M >> 8;                        // 32 m-tiles
  const int n0 = (lin / mt) * 128;
  const int m0 = (lin % mt) * 256;

  const f32x4 vzero = {0.f, 0.f, 0.f, 0.f};
  f32x4 acc[8][2];
#pragma unroll
  for (int i = 0; i < 8; i++)
#pragma unroll
    for (int j = 0; j < 2; j++) acc[i][j] = vzero;

  const int sl = lane >> 3, ss = lane & 7;
  const int swzs = (ss ^ sl) * 8;              // pre-swizzled source chunk
  const uint16_t* a0 = A + (size_t)(m0 + wid * 32 + sl) * K + swzs;
  const uint16_t* b0 = BT + (size_t)(n0 + wid * 16 + sl) * K + swzs;
  const size_t r8 = (size_t)8 * K;

#define STAGE_A2(bsel, t)                                                 \
  do {                                                                    \
    const int ko_ = (t) * 64;                                             \
    gload_lds16(a0 + ko_,          &As[bsel][(wid * 32 + 0) * 64]);       \
    gload_lds16(a0 + r8 + ko_,     &As[bsel][(wid * 32 + 8) * 64]);       \
    gload_lds16(a0 + 2 * r8 + ko_, &As[bsel][(wid * 32 + 16) * 64]);      \
    gload_lds16(a0 + 3 * r8 + ko_, &As[bsel][(wid * 32 + 24) * 64]);      \
  } while (0)
#define STAGE_B2(bsel, t)                                                 \
  do {                                                                    \
    const int ko_ = (t) * 64;                                             \
    gload_lds16(b0 + ko_,      &Bs[bsel][(wid * 16 + 0) * 64]);           \
    gload_lds16(b0 + r8 + ko_, &Bs[bsel][(wid * 16 + 8) * 64]);           \
  } while (0)

  const int nt = K >> 6;   // 16
  const int fsw = lr & 7;
  STAGE_A2(0, 0);
  STAGE_B2(0, 0);
  __syncthreads();

  for (int t = 0; t < nt; ++t) {
    const int cur = t & 1;
    const int nxt = cur ^ 1;

    // B fragments for the whole tile (4 x b128); rows wc*32 + nj*16 + lr in [0,128)
    short8 bf[2][2];
#pragma unroll
    for (int nj = 0; nj < 2; ++nj)
#pragma unroll
      for (int ks = 0; ks < 2; ++ks)
        bf[nj][ks] = *reinterpret_cast<const short8*>(
            &Bs[cur][(wc * 32 + nj * 16 + lr) * 64 + (((ks * 4 + lg) ^ fsw) * 8)]);

#define PHASE2(mi0)                                                           \
  do {                                                                        \
    short8 af0k0 = *reinterpret_cast<const short8*>(                          \
        &As[cur][(wr * 128 + (mi0) * 16 + lr) * 64 + (((0 * 4 + lg) ^ fsw) * 8)]); \
    short8 af0k1 = *reinterpret_cast<const short8*>(                          \
        &As[cur][(wr * 128 + (mi0) * 16 + lr) * 64 + (((1 * 4 + lg) ^ fsw) * 8)]); \
    short8 af1k0 = *reinterpret_cast<const short8*>(                          \
        &As[cur][(wr * 128 + (mi0 + 1) * 16 + lr) * 64 + (((0 * 4 + lg) ^ fsw) * 8)]); \
    short8 af1k1 = *reinterpret_cast<const short8*>(                          \
        &As[cur][(wr * 128 + (mi0 + 1) * 16 + lr) * 64 + (((1 * 4 + lg) ^ fsw) * 8)]); \
    __builtin_amdgcn_s_setprio(1);                                            \
    _Pragma("unroll")                                                         \
    for (int nj = 0; nj < 2; ++nj) {                                          \
      acc[mi0][nj] = __builtin_amdgcn_mfma_f32_16x16x32_bf16(af0k0, bf[nj][0], acc[mi0][nj], 0, 0, 0); \
      acc[mi0][nj] = __builtin_amdgcn_mfma_f32_16x16x32_bf16(af0k1, bf[nj][1], acc[mi0][nj], 0, 0, 0); \
      acc[mi0 + 1][nj] = __builtin_amdgcn_mfma_f32_16x16x32_bf16(af1k0, bf[nj][0], acc[mi0 + 1][nj], 0, 0, 0); \
      acc[mi0 + 1][nj] = __builtin_amdgcn_mfma_f32_16x16x32_bf16(af1k1, bf[nj][1], acc[mi0 + 1][nj], 0, 0, 0); \
    }                                                                         \
    __builtin_amdgcn_s_setprio(0);                                            \
  } while (0)

    if (t + 1 < nt) STAGE_A2(nxt, t + 1);
    PHASE2(0);
    if (t + 1 < nt) STAGE_B2(nxt, t + 1);
    PHASE2(2);
    PHASE2(4);
    PHASE2(6);
#undef PHASE2

    __syncthreads();
  }
#undef STAGE_A2
#undef STAGE_B2

#pragma unroll
  for (int nj = 0; nj < 2; nj++) {
    int col = n0 + wc * 32 + nj * 16 + lr;
    float bv = bias[col];
#pragma unroll
    for (int mi = 0; mi < 8; mi++) {
      int rowb = m0 + wr * 128 + mi * 16 + lg * 4;
#pragma unroll
      for (int r = 0; r < 4; r++)
        Cout[(size_t)(rowb + r) * N + col] = acc[mi][nj][r] + bv;
    }
  }
}

// -------- causal flash attention: 32x32 MFMA, in-register P via permlane32_swap --------
// Verified round-11/15 kernel (113.5 us, VGPR=80 — AT a VGPR occupancy cliff; do not
// add registers). UNCHANGED.
#define KVB 64
__global__ void __launch_bounds__(256) k_attn(const uint16_t* __restrict__ qkv,
                                              const uint16_t* __restrict__ vT,
                                              uint16_t* __restrict__ out) {
  __shared__ __align__(16) char lds[32768];  // K dbuf 16K | V dbuf 16K (epilogue reuses)
  const int tid = threadIdx.x;
  const int lane = tid & 63, wid = tid >> 6;
  const int l31 = lane & 31, hi = lane >> 5;
  const int hi4 = hi * 4;

  const int bid = blockIdx.x;
  const int xcd = bid & 7, j = bid >> 3;   // j 0..127
  const int bh = xcd * 4 + (j & 3);
  const int qt = 31 - (j >> 2);            // heavy first
  const int b = bh >> 4, h = bh & 15;
  const int q0 = qt * 128;
  const size_t rowbase = (size_t)b * T_SEQ;
  const int hoff = h * 192;
  const uint16_t* Kg = qkv + rowbase * 3072 + hoff + 64;  // K rows stride 3072
  const uint16_t* Vg = vT + (size_t)bh * 64 * T_SEQ;      // V^T rows stride 4096

  const int sr = tid >> 3, sc = tid & 7;
  const int wsw = (sc ^ (sr & 7)) * 16;
  const float C_SC = 0.180336881f;  // log2(e)/8, folded into Q

  int rslot[4];
#pragma unroll
  for (int c = 0; c < 4; c++) rslot[c] = (((2 * c + hi) ^ (lane & 7)) << 4);
  const int rowb128 = l31 * 128;

  const int qrow = q0 + wid * 32 + l31;
  short8 qf[4];
#pragma unroll
  for (int ks = 0; ks < 4; ks++) {
    short8 raw = *reinterpret_cast<const short8*>(
        qkv + (rowbase + qrow) * 3072 + hoff + hi * 8 + ks * 16);
    union { short8 s; uint32_t u[4]; } pk;
#pragma unroll
    for (int e = 0; e < 4; e++) {
      float f0 = __uint_as_float(((uint32_t)(uint16_t)raw[2 * e]) << 16) * C_SC;
      float f1 = __uint_as_float(((uint32_t)(uint16_t)raw[2 * e + 1]) << 16) * C_SC;
      asm("v_cvt_pk_bf16_f32 %0, %1, %2" : "=v"(pk.u[e]) : "v"(f0), "v"(f1));
    }
    qf[ks] = pk.s;
  }

  f32x16 o0, o1, zero16;
#pragma unroll
  for (int i = 0; i < 16; i++) zero16[i] = 0.f;
  o0 = zero16; o1 = zero16;
  float lpart = 0.f;

  const int nkt = 2 * qt + 2;
  const int qwmax = q0 + wid * 32 + 31;

  short8 rk0, rk1, rv0, rv1;
  rk0 = *reinterpret_cast<const short8*>(Kg + (size_t)sr * 3072 + sc * 8);
  rk1 = *reinterpret_cast<const short8*>(Kg + (size_t)(sr + 32) * 3072 + sc * 8);
  rv0 = *reinterpret_cast<const short8*>(Vg + (size_t)sr * T_SEQ + sc * 8);
  rv1 = *reinterpret_cast<const short8*>(Vg + (size_t)(sr + 32) * T_SEQ + sc * 8);
  {
    char* kb0 = lds;
    char* vb0 = lds + 16384;
    *reinterpret_cast<short8*>(kb0 + sr * 128 + wsw) = rk0;
    *reinterpret_cast<short8*>(kb0 + (sr + 32) * 128 + wsw) = rk1;
    *reinterpret_cast<short8*>(vb0 + sr * 128 + wsw) = rv0;
    *reinterpret_cast<short8*>(vb0 + (sr + 32) * 128 + wsw) = rv1;
  }
  if (nkt > 1) {
    rk0 = *reinterpret_cast<const short8*>(Kg + (size_t)(KVB + sr) * 3072 + sc * 8);
    rk1 = *reinterpret_cast<const short8*>(Kg + (size_t)(KVB + sr + 32) * 3072 + sc * 8);
    rv0 = *reinterpret_cast<const short8*>(Vg + (size_t)sr * T_SEQ + KVB + sc * 8);
    rv1 = *reinterpret_cast<const short8*>(Vg + (size_t)(sr + 32) * T_SEQ + KVB + sc * 8);
  }

  for (int kt = 0; kt < nkt; kt++) {
    __syncthreads();  // prev writes visible; prev reads done
    if (kt + 1 < nkt) {
      const int nsel = (kt + 1) & 1;
      char* kb = lds + (nsel ? 8192 : 0);
      char* vb = lds + 16384 + (nsel ? 8192 : 0);
      *reinterpret_cast<short8*>(kb + sr * 128 + wsw) = rk0;
      *reinterpret_cast<short8*>(kb + (sr + 32) * 128 + wsw) = rk1;
      *reinterpret_cast<short8*>(vb + sr * 128 + wsw) = rv0;
      *reinterpret_cast<short8*>(vb + (sr + 32) * 128 + wsw) = rv1;
      if (kt + 2 < nkt) {
        int k0n = (kt + 2) * KVB;
        rk0 = *reinterpret_cast<const short8*>(Kg + (size_t)(k0n + sr) * 3072 + sc * 8);
        rk1 = *reinterpret_cast<const short8*>(Kg + (size_t)(k0n + sr + 32) * 3072 + sc * 8);
        rv0 = *reinterpret_cast<const short8*>(Vg + (size_t)sr * T_SEQ + k0n + sc * 8);
        rv1 = *reinterpret_cast<const short8*>(Vg + (size_t)(sr + 32) * T_SEQ + k0n + sc * 8);
      }
    }

    if (kt * KVB <= qwmax) {
      const int csel = kt & 1;
      char* kcur = lds + (csel ? 8192 : 0);
      char* vcur = lds + 16384 + (csel ? 8192 : 0);
      const int ktb = kt * KVB;
      const bool notfull = (ktb + 63 > q0 + wid * 32);

      // ---- QK^T: s0 = keys[0..31], s1 = keys[32..63] (x32 q) ----
      f32x16 s0 = zero16, s1 = zero16;
      __builtin_amdgcn_s_setprio(1);
#pragma unroll
      for (int ks = 0; ks < 4; ks++) {
        short8 kf0 = *reinterpret_cast<const short8*>(kcur + rowb128 + rslot[ks]);
        short8 kf1 = *reinterpret_cast<const short8*>(kcur + 4096 + rowb128 + rslot[ks]);
        s0 = __builtin_amdgcn_mfma_f32_32x32x16_bf16(kf0, qf[ks], s0, 0, 0, 0);
        s1 = __builtin_amdgcn_mfma_f32_32x32x16_bf16(kf1, qf[ks], s1, 0, 0, 0);
      }
      __builtin_amdgcn_s_setprio(0);

      uint32_t u0[8], u1[8];
#define SMAX_KB(SV, KB, U)                                                    \
  do {                                                                        \
    _Pragma("unroll")                                                         \
    for (int r = 0; r < 16; r++) {                                            \
      float v = SV[r];                                                        \
      if (notfull) {                                                          \
        int key = ktb + (KB) * 32 + (r & 3) + 8 * (r >> 2) + hi4;             \
        if (key > qrow) v = -INFINITY;                                        \
      }                                                                       \
      float p = __builtin_amdgcn_exp2f(v);                                    \
      SV[r] = p;                                                              \
      lpart += p;                                                             \
    }                                                                         \
    _Pragma("unroll")                                                         \
    for (int jj = 0; jj < 8; jj++)                                            \
      asm("v_cvt_pk_bf16_f32 %0, %1, %2"                                      \
          : "=v"(U[jj]) : "v"(SV[2 * jj]), "v"(SV[2 * jj + 1]));              \
    asm volatile("v_permlane32_swap_b32 %0, %1" : "+v"(U[0]), "+v"(U[2]));    \
    asm volatile("v_permlane32_swap_b32 %0, %1" : "+v"(U[1]), "+v"(U[3]));    \
    asm volatile("v_permlane32_swap_b32 %0, %1" : "+v"(U[4]), "+v"(U[6]));    \
    asm volatile("v_permlane32_swap_b32 %0, %1" : "+v"(U[5]), "+v"(U[7]));    \
  } while (0)

      SMAX_KB(s0, 0, u0);
      SMAX_KB(s1, 1, u1);
#undef SMAX_KB

      union { uint32_t u[4]; short8 s; } pf;
      __builtin_amdgcn_s_setprio(1);
#pragma unroll
      for (int kv = 0; kv < 4; kv++) {
        if (kv == 0) { pf.u[0] = u0[0]; pf.u[1] = u0[1]; pf.u[2] = u0[2]; pf.u[3] = u0[3]; }
        else if (kv == 1) { pf.u[0] = u0[4]; pf.u[1] = u0[5]; pf.u[2] = u0[6]; pf.u[3] = u0[7]; }
        else if (kv == 2) { pf.u[0] = u1[0]; pf.u[1] = u1[1]; pf.u[2] = u1[2]; pf.u[3] = u1[3]; }
        else { pf.u[0] = u1[4]; pf.u[1] = u1[5]; pf.u[2] = u1[6]; pf.u[3] = u1[7]; }
        short8 vf0 = *reinterpret_cast<const short8*>(vcur + rowb128 + rslot[kv]);
        short8 vf1 = *reinterpret_cast<const short8*>(vcur + 4096 + rowb128 + rslot[kv]);
        o0 = __builtin_amdgcn_mfma_f32_32x32x16_bf16(vf0, pf.s, o0, 0, 0, 0);
        o1 = __builtin_amdgcn_mfma_f32_32x32x16_bf16(vf1, pf.s, o1, 0, 0, 0);
      }
      __builtin_amdgcn_s_setprio(0);
    }
  }

  // ---- epilogue ----
  __syncthreads();
  float ltot = lpart + __shfl_xor(lpart, 32);
  float inv = 1.0f / ltot;
  char* scrb = lds + wid * 8192;  // per-wave 8KB: [32 q][16 slots x 16B]
#pragma unroll
  for (int g = 0; g < 4; g++) {
    f32x4 w0, w1;
#pragma unroll
    for (int e = 0; e < 4; e++) { w0[e] = o0[4 * g + e] * inv; w1[e] = o1[4 * g + e] * inv; }
    int s0i = 2 * g + hi, s1i = s0i + 8;
    *reinterpret_cast<f32x4*>(scrb + l31 * 256 + ((s0i ^ (l31 & 7)) << 4)) = w0;
    *reinterpret_cast<f32x4*>(scrb + l31 * 256 + ((s1i ^ (l31 & 7)) << 4)) = w1;
  }
  asm volatile("s_waitcnt lgkmcnt(0)" ::: "memory");
  __builtin_amdgcn_sched_barrier(0);
  {
    int row = lane >> 1, half = lane & 1;
    uint16_t tmp[32];
#pragma unroll
    for (int k = 0; k < 8; k++) {
      f32x4 vv = *reinterpret_cast<const f32x4*>(
          scrb + row * 256 + (((half * 8 + k) ^ (row & 7)) << 4));
#pragma unroll
      for (int e = 0; e < 4; e++) tmp[k * 4 + e] = f2bf(vv[e]);
    }
    uint16_t* op = out + (rowbase + q0 + wid * 32 + row) * 1024 + h * 64 + half * 32;
#pragma unroll
    for (int k = 0; k < 4; k++)
      *reinterpret_cast<short8*>(op + k * 8) = *reinterpret_cast<const short8*>(tmp + k * 8);
  }
}

extern "C" void kernel_launch(void* const* d_in, const int* in_sizes, int n_in,
                              void* d_out, int out_size, void* d_ws, size_t ws_size,
                              hipStream_t stream) {
  const float* x = (const float*)d_in[0];
  const float* w_qkv = (const float*)d_in[1];
  const float* b_qkv = (const float*)d_in[2];
  const float* w_out = (const float*)d_in[3];
  const float* b_out = (const float*)d_in[4];
  float* out = (float*)d_out;

  uint8_t* ws = (uint8_t*)d_ws;
  uint16_t* x_bf  = (uint16_t*)(ws);                         // 16 MB (reused as attn_out)
  uint16_t* wqkvT = (uint16_t*)(ws + (16u << 20));           // 6 MB
  uint16_t* woutT = (uint16_t*)(ws + (22u << 20));           // 2 MB
  uint16_t* qkv   = (uint16_t*)(ws + (24u << 20));           // 48 MB
  uint16_t* vTbuf = (uint16_t*)(ws + (72u << 20));           // 16 MB
  uint16_t* attn_o = x_bf;

  k_cvt<<<8192, 256, 0, stream>>>(x, x_bf, 2097152);
  k_tc<<<dim3(96, 32), 256, 0, stream>>>(w_qkv, wqkvT, 1024, 3072);
  k_tc<<<dim3(32, 32), 256, 0, stream>>>(w_out, woutT, 1024, 1024);
  // GEMM1: 256x256 phase-split tiles -> 32*12 = 384 blocks (%8==0)
  k_gemm256p<<<384, 512, 0, stream>>>(x_bf, wqkvT, b_qkv, qkv, 8192, 3072, 1024);
  k_vt<<<dim3(64, 32), 256, 0, stream>>>(qkv, vTbuf);
  k_attn<<<1024, 256, 0, stream>>>(qkv, vTbuf, attn_o);
  // GEMM2: 256x128 phase-split tiles -> 32*8 = 256 blocks (exactly 1 dispatch round)
  k_gemm2<<<256, 512, 0, stream>>>(attn_o, woutT, b_out, out, 8192, 1024, 1024);
}

// Round 20
// 220.174 us; speedup vs baseline: 1.0175x; 1.0175x over previous
//
#include <hip/hip_runtime.h>
#include <stdint.h>
#include <math.h>

#define T_SEQ 4096

typedef __attribute__((ext_vector_type(8))) short short8;
typedef __attribute__((ext_vector_type(4))) float f32x4;
typedef __attribute__((ext_vector_type(16))) float f32x16;
typedef __attribute__((ext_vector_type(4))) uint16_t u16x4;

__device__ __forceinline__ uint16_t f2bf(float f) {
  uint32_t u = __float_as_uint(f);
  u += 0x7FFFu + ((u >> 16) & 1u);
  return (uint16_t)(u >> 16);
}

// async global->LDS, 16B per lane; LDS dest is wave-uniform base + lane*16
__device__ __forceinline__ void gload_lds16(const uint16_t* g, uint16_t* l) {
  __builtin_amdgcn_global_load_lds(
      (const __attribute__((address_space(1))) void*)g,
      (__attribute__((address_space(3))) void*)l, 16, 0, 0);
}

// ---------------- convert x: f32 -> bf16 ----------------
__global__ void __launch_bounds__(256) k_cvt(const float* __restrict__ in,
                                             uint16_t* __restrict__ out, int n4) {
  int i = blockIdx.x * 256 + threadIdx.x;
  if (i >= n4) return;
  float4 v = reinterpret_cast<const float4*>(in)[i];
  u16x4 o = { f2bf(v.x), f2bf(v.y), f2bf(v.z), f2bf(v.w) };
  reinterpret_cast<u16x4*>(out)[i] = o;
}

// ------------- transpose+convert: w (RxC f32) -> wt (CxR bf16) -------------
__global__ void __launch_bounds__(256) k_tc(const float* __restrict__ w,
                                            uint16_t* __restrict__ wt, int R, int C) {
  __shared__ uint16_t tile[32][33];
  int tx = threadIdx.x & 31, ty = threadIdx.x >> 5;
  int r0 = blockIdx.y * 32, c0 = blockIdx.x * 32;
#pragma unroll
  for (int i = 0; i < 4; i++)
    tile[ty + 8 * i][tx] = f2bf(w[(size_t)(r0 + ty + 8 * i) * C + c0 + tx]);
  __syncthreads();
#pragma unroll
  for (int i = 0; i < 4; i++)
    wt[(size_t)(c0 + ty + 8 * i) * R + r0 + tx] = tile[tx][ty + 8 * i];
}

// -------- transpose V out of qkv: vT[bh*64+d][t] (t local to batch) --------
__global__ void __launch_bounds__(256) k_vt(const uint16_t* __restrict__ qkv,
                                            uint16_t* __restrict__ vT) {
  __shared__ uint16_t tile[64][65];
  const int bh = blockIdx.y, b = bh >> 4, h = bh & 15;
  const int t0 = blockIdx.x * 64;
  const int tid = threadIdx.x;
  const int r = tid >> 3, c8 = tid & 7;
  const uint16_t* src = qkv + ((size_t)b * T_SEQ + t0) * 3072 + h * 192 + 128;
#pragma unroll
  for (int i = 0; i < 2; i++) {
    int row = r + 32 * i;
    short8 v = *reinterpret_cast<const short8*>(src + (size_t)row * 3072 + c8 * 8);
#pragma unroll
    for (int j = 0; j < 8; j++) tile[row][c8 * 8 + j] = (uint16_t)v[j];
  }
  __syncthreads();
  uint16_t* dst = vT + ((size_t)bh * 64) * T_SEQ + t0;
#pragma unroll
  for (int i = 0; i < 2; i++) {
    int d = r + 32 * i;
    short8 v;
#pragma unroll
    for (int j = 0; j < 8; j++) v[j] = (short)tile[c8 * 8 + j][d];
    *reinterpret_cast<short8*>(dst + (size_t)d * T_SEQ + c8 * 8) = v;
  }
}

// ---- GEMM (128x128, BK=64, dbuf, swizzled): used for the N=1024 GEMM ----
template <int BF16_OUT>
__global__ void __launch_bounds__(256, 2) k_gemm(const uint16_t* __restrict__ A,
                                                 const uint16_t* __restrict__ BT,
                                                 const float* __restrict__ bias,
                                                 void* __restrict__ Cout,
                                                 int M, int N, int K) {
  __shared__ __align__(16) uint16_t As[2][128 * 64];
  __shared__ __align__(16) uint16_t Bs[2][128 * 64];
  const int tid = threadIdx.x;
  const int lane = tid & 63, wid = tid >> 6;
  const int lr = lane & 15, lg = lane >> 4;
  const int wr = wid >> 1, wc = wid & 1;

  const int bid = blockIdx.x;
  const int cpx = gridDim.x >> 3;
  const int lin = (bid & 7) * cpx + (bid >> 3);
  const int mt = M >> 7;
  const int n0 = (lin / mt) * 128;
  const int m0 = (lin % mt) * 128;

  const f32x4 vzero = {0.f, 0.f, 0.f, 0.f};
  f32x4 acc[4][4];
#pragma unroll
  for (int i = 0; i < 4; i++)
#pragma unroll
    for (int j = 0; j < 4; j++) acc[i][j] = vzero;

  const int sl = lane >> 3, ss = lane & 7;
  const int swzs = (ss ^ sl) * 8;
  const uint16_t* a0 = A + (size_t)(m0 + wid * 32 + sl) * K + swzs;
  const uint16_t* b0 = BT + (size_t)(n0 + wid * 32 + sl) * K + swzs;
  const size_t r8 = (size_t)8 * K;

#define STAGE(bsel, t)                                                   \
  do {                                                                   \
    const int koff_ = (t) * 64;                                          \
    gload_lds16(a0 + koff_,          &As[bsel][(wid * 32 + 0) * 64]);    \
    gload_lds16(a0 + r8 + koff_,     &As[bsel][(wid * 32 + 8) * 64]);    \
    gload_lds16(a0 + 2 * r8 + koff_, &As[bsel][(wid * 32 + 16) * 64]);   \
    gload_lds16(a0 + 3 * r8 + koff_, &As[bsel][(wid * 32 + 24) * 64]);   \
    gload_lds16(b0 + koff_,          &Bs[bsel][(wid * 32 + 0) * 64]);    \
    gload_lds16(b0 + r8 + koff_,     &Bs[bsel][(wid * 32 + 8) * 64]);    \
    gload_lds16(b0 + 2 * r8 + koff_, &Bs[bsel][(wid * 32 + 16) * 64]);   \
    gload_lds16(b0 + 3 * r8 + koff_, &Bs[bsel][(wid * 32 + 24) * 64]);   \
  } while (0)

  const int nt = K >> 6;
  const int fsw = lr & 7;
  STAGE(0, 0);
  STAGE(1, 1);
  __syncthreads();

  for (int t = 0; t < nt; ++t) {
    const int cur = t & 1;
#pragma unroll
    for (int ks = 0; ks < 2; ++ks) {
      const int col = (((ks * 4 + lg) ^ fsw) * 8);
      short8 af[4], bf[4];
#pragma unroll
      for (int mi = 0; mi < 4; ++mi)
        af[mi] = *reinterpret_cast<const short8*>(
            &As[cur][(wr * 64 + mi * 16 + lr) * 64 + col]);
#pragma unroll
      for (int nj = 0; nj < 4; ++nj)
        bf[nj] = *reinterpret_cast<const short8*>(
            &Bs[cur][(wc * 64 + nj * 16 + lr) * 64 + col]);
      __builtin_amdgcn_s_setprio(1);
#pragma unroll
      for (int mi = 0; mi < 4; ++mi)
#pragma unroll
        for (int nj = 0; nj < 4; ++nj)
          acc[mi][nj] = __builtin_amdgcn_mfma_f32_16x16x32_bf16(af[mi], bf[nj], acc[mi][nj], 0, 0, 0);
      __builtin_amdgcn_s_setprio(0);
    }
    __syncthreads();
    if (t + 2 < nt) STAGE(cur, t + 2);
  }
#undef STAGE

#pragma unroll
  for (int nj = 0; nj < 4; nj++) {
    int col = n0 + wc * 64 + nj * 16 + lr;
    float bv = bias[col];
#pragma unroll
    for (int mi = 0; mi < 4; mi++) {
      int rowb = m0 + wr * 64 + mi * 16 + lg * 4;
#pragma unroll
      for (int r = 0; r < 4; r++) {
        float v = acc[mi][nj][r] + bv;
        if (BF16_OUT)
          ((uint16_t*)Cout)[(size_t)(rowb + r) * N + col] = f2bf(v);
        else
          ((float*)Cout)[(size_t)(rowb + r) * N + col] = v;
      }
    }
  }
}

// ---- GEMM1 256x256, 8 waves (2x4), per-wave 128x64, BK=64, dbuf, phase-split ----
// (verified round 18, +7us vs 128^2) LDS 128KB (1 block/CU). Phys chunk = logical ^
// row&7; staging source chunk (l&7)^(l>>3). Tile t+1: A staged phase 0, B phase 1.
__global__ void __launch_bounds__(512, 1) k_gemm256p(const uint16_t* __restrict__ A,
                                                     const uint16_t* __restrict__ BT,
                                                     const float* __restrict__ bias,
                                                     uint16_t* __restrict__ Cout,
                                                     int M, int N, int K) {
  __shared__ __align__(16) uint16_t As[2][256 * 64];
  __shared__ __align__(16) uint16_t Bs[2][256 * 64];
  const int tid = threadIdx.x;
  const int lane = tid & 63, wid = tid >> 6;   // 8 waves
  const int lr = lane & 15, lg = lane >> 4;
  const int wr = wid >> 2, wc = wid & 3;       // 2 x 4 wave grid

  const int bid = blockIdx.x;
  const int cpx = gridDim.x >> 3;
  const int lin = (bid & 7) * cpx + (bid >> 3);
  const int mt = M >> 8;
  const int n0 = (lin / mt) * 256;
  const int m0 = (lin % mt) * 256;

  const f32x4 vzero = {0.f, 0.f, 0.f, 0.f};
  f32x4 acc[8][4];
#pragma unroll
  for (int i = 0; i < 8; i++)
#pragma unroll
    for (int j = 0; j < 4; j++) acc[i][j] = vzero;

  const int sl = lane >> 3, ss = lane & 7;
  const int swzs = (ss ^ sl) * 8;              // pre-swizzled source chunk
  const uint16_t* a0 = A + (size_t)(m0 + wid * 32 + sl) * K + swzs;
  const uint16_t* b0 = BT + (size_t)(n0 + wid * 32 + sl) * K + swzs;
  const size_t r8 = (size_t)8 * K;

#define STAGE_A(bsel, t)                                                  \
  do {                                                                    \
    const int ko_ = (t) * 64;                                             \
    gload_lds16(a0 + ko_,          &As[bsel][(wid * 32 + 0) * 64]);       \
    gload_lds16(a0 + r8 + ko_,     &As[bsel][(wid * 32 + 8) * 64]);       \
    gload_lds16(a0 + 2 * r8 + ko_, &As[bsel][(wid * 32 + 16) * 64]);      \
    gload_lds16(a0 + 3 * r8 + ko_, &As[bsel][(wid * 32 + 24) * 64]);      \
  } while (0)
#define STAGE_B(bsel, t)                                                  \
  do {                                                                    \
    const int ko_ = (t) * 64;                                             \
    gload_lds16(b0 + ko_,          &Bs[bsel][(wid * 32 + 0) * 64]);       \
    gload_lds16(b0 + r8 + ko_,     &Bs[bsel][(wid * 32 + 8) * 64]);       \
    gload_lds16(b0 + 2 * r8 + ko_, &Bs[bsel][(wid * 32 + 16) * 64]);      \
    gload_lds16(b0 + 3 * r8 + ko_, &Bs[bsel][(wid * 32 + 24) * 64]);      \
  } while (0)

  const int nt = K >> 6;   // 16
  const int fsw = lr & 7;
  STAGE_A(0, 0);
  STAGE_B(0, 0);
  __syncthreads();  // drains prologue loads

  for (int t = 0; t < nt; ++t) {
    const int cur = t & 1;
    const int nxt = cur ^ 1;

    short8 bf[4][2];
#pragma unroll
    for (int nj = 0; nj < 4; ++nj)
#pragma unroll
      for (int ks = 0; ks < 2; ++ks)
        bf[nj][ks] = *reinterpret_cast<const short8*>(
            &Bs[cur][(wc * 64 + nj * 16 + lr) * 64 + (((ks * 4 + lg) ^ fsw) * 8)]);

#define PHASE(mi0)                                                            \
  do {                                                                        \
    short8 af0k0 = *reinterpret_cast<const short8*>(                          \
        &As[cur][(wr * 128 + (mi0) * 16 + lr) * 64 + (((0 * 4 + lg) ^ fsw) * 8)]); \
    short8 af0k1 = *reinterpret_cast<const short8*>(                          \
        &As[cur][(wr * 128 + (mi0) * 16 + lr) * 64 + (((1 * 4 + lg) ^ fsw) * 8)]); \
    short8 af1k0 = *reinterpret_cast<const short8*>(                          \
        &As[cur][(wr * 128 + (mi0 + 1) * 16 + lr) * 64 + (((0 * 4 + lg) ^ fsw) * 8)]); \
    short8 af1k1 = *reinterpret_cast<const short8*>(                          \
        &As[cur][(wr * 128 + (mi0 + 1) * 16 + lr) * 64 + (((1 * 4 + lg) ^ fsw) * 8)]); \
    __builtin_amdgcn_s_setprio(1);                                            \
    _Pragma("unroll")                                                         \
    for (int nj = 0; nj < 4; ++nj) {                                          \
      acc[mi0][nj] = __builtin_amdgcn_mfma_f32_16x16x32_bf16(af0k0, bf[nj][0], acc[mi0][nj], 0, 0, 0); \
      acc[mi0][nj] = __builtin_amdgcn_mfma_f32_16x16x32_bf16(af0k1, bf[nj][1], acc[mi0][nj], 0, 0, 0); \
      acc[mi0 + 1][nj] = __builtin_amdgcn_mfma_f32_16x16x32_bf16(af1k0, bf[nj][0], acc[mi0 + 1][nj], 0, 0, 0); \
      acc[mi0 + 1][nj] = __builtin_amdgcn_mfma_f32_16x16x32_bf16(af1k1, bf[nj][1], acc[mi0 + 1][nj], 0, 0, 0); \
    }                                                                         \
    __builtin_amdgcn_s_setprio(0);                                            \
  } while (0)

    if (t + 1 < nt) STAGE_A(nxt, t + 1);
    PHASE(0);
    if (t + 1 < nt) STAGE_B(nxt, t + 1);
    PHASE(2);
    PHASE(4);
    PHASE(6);
#undef PHASE

    __syncthreads();
  }
#undef STAGE_A
#undef STAGE_B

#pragma unroll
  for (int nj = 0; nj < 4; nj++) {
    int col = n0 + wc * 64 + nj * 16 + lr;
    float bv = bias[col];
#pragma unroll
    for (int mi = 0; mi < 8; mi++) {
      int rowb = m0 + wr * 128 + mi * 16 + lg * 4;
#pragma unroll
      for (int r = 0; r < 4; r++)
        Cout[(size_t)(rowb + r) * N + col] = f2bf(acc[mi][nj][r] + bv);
    }
  }
}

// -------- causal flash attention: 32x32 MFMA, in-register P via permlane32_swap --------
// Verified round-11/15 kernel (113.5 us, VGPR=80 — AT a VGPR occupancy cliff; do not
// add registers). UNCHANGED.
#define KVB 64
__global__ void __launch_bounds__(256) k_attn(const uint16_t* __restrict__ qkv,
                                              const uint16_t* __restrict__ vT,
                                              uint16_t* __restrict__ out) {
  __shared__ __align__(16) char lds[32768];  // K dbuf 16K | V dbuf 16K (epilogue reuses)
  const int tid = threadIdx.x;
  const int lane = tid & 63, wid = tid >> 6;
  const int l31 = lane & 31, hi = lane >> 5;
  const int hi4 = hi * 4;

  const int bid = blockIdx.x;
  const int xcd = bid & 7, j = bid >> 3;   // j 0..127
  const int bh = xcd * 4 + (j & 3);
  const int qt = 31 - (j >> 2);            // heavy first
  const int b = bh >> 4, h = bh & 15;
  const int q0 = qt * 128;
  const size_t rowbase = (size_t)b * T_SEQ;
  const int hoff = h * 192;
  const uint16_t* Kg = qkv + rowbase * 3072 + hoff + 64;  // K rows stride 3072
  const uint16_t* Vg = vT + (size_t)bh * 64 * T_SEQ;      // V^T rows stride 4096

  const int sr = tid >> 3, sc = tid & 7;
  const int wsw = (sc ^ (sr & 7)) * 16;
  const float C_SC = 0.180336881f;  // log2(e)/8, folded into Q

  int rslot[4];
#pragma unroll
  for (int c = 0; c < 4; c++) rslot[c] = (((2 * c + hi) ^ (lane & 7)) << 4);
  const int rowb128 = l31 * 128;

  const int qrow = q0 + wid * 32 + l31;
  short8 qf[4];
#pragma unroll
  for (int ks = 0; ks < 4; ks++) {
    short8 raw = *reinterpret_cast<const short8*>(
        qkv + (rowbase + qrow) * 3072 + hoff + hi * 8 + ks * 16);
    union { short8 s; uint32_t u[4]; } pk;
#pragma unroll
    for (int e = 0; e < 4; e++) {
      float f0 = __uint_as_float(((uint32_t)(uint16_t)raw[2 * e]) << 16) * C_SC;
      float f1 = __uint_as_float(((uint32_t)(uint16_t)raw[2 * e + 1]) << 16) * C_SC;
      asm("v_cvt_pk_bf16_f32 %0, %1, %2" : "=v"(pk.u[e]) : "v"(f0), "v"(f1));
    }
    qf[ks] = pk.s;
  }

  f32x16 o0, o1, zero16;
#pragma unroll
  for (int i = 0; i < 16; i++) zero16[i] = 0.f;
  o0 = zero16; o1 = zero16;
  float lpart = 0.f;

  const int nkt = 2 * qt + 2;
  const int qwmax = q0 + wid * 32 + 31;

  short8 rk0, rk1, rv0, rv1;
  rk0 = *reinterpret_cast<const short8*>(Kg + (size_t)sr * 3072 + sc * 8);
  rk1 = *reinterpret_cast<const short8*>(Kg + (size_t)(sr + 32) * 3072 + sc * 8);
  rv0 = *reinterpret_cast<const short8*>(Vg + (size_t)sr * T_SEQ + sc * 8);
  rv1 = *reinterpret_cast<const short8*>(Vg + (size_t)(sr + 32) * T_SEQ + sc * 8);
  {
    char* kb0 = lds;
    char* vb0 = lds + 16384;
    *reinterpret_cast<short8*>(kb0 + sr * 128 + wsw) = rk0;
    *reinterpret_cast<short8*>(kb0 + (sr + 32) * 128 + wsw) = rk1;
    *reinterpret_cast<short8*>(vb0 + sr * 128 + wsw) = rv0;
    *reinterpret_cast<short8*>(vb0 + (sr + 32) * 128 + wsw) = rv1;
  }
  if (nkt > 1) {
    rk0 = *reinterpret_cast<const short8*>(Kg + (size_t)(KVB + sr) * 3072 + sc * 8);
    rk1 = *reinterpret_cast<const short8*>(Kg + (size_t)(KVB + sr + 32) * 3072 + sc * 8);
    rv0 = *reinterpret_cast<const short8*>(Vg + (size_t)sr * T_SEQ + KVB + sc * 8);
    rv1 = *reinterpret_cast<const short8*>(Vg + (size_t)(sr + 32) * T_SEQ + KVB + sc * 8);
  }

  for (int kt = 0; kt < nkt; kt++) {
    __syncthreads();  // prev writes visible; prev reads done
    if (kt + 1 < nkt) {
      const int nsel = (kt + 1) & 1;
      char* kb = lds + (nsel ? 8192 : 0);
      char* vb = lds + 16384 + (nsel ? 8192 : 0);
      *reinterpret_cast<short8*>(kb + sr * 128 + wsw) = rk0;
      *reinterpret_cast<short8*>(kb + (sr + 32) * 128 + wsw) = rk1;
      *reinterpret_cast<short8*>(vb + sr * 128 + wsw) = rv0;
      *reinterpret_cast<short8*>(vb + (sr + 32) * 128 + wsw) = rv1;
      if (kt + 2 < nkt) {
        int k0n = (kt + 2) * KVB;
        rk0 = *reinterpret_cast<const short8*>(Kg + (size_t)(k0n + sr) * 3072 + sc * 8);
        rk1 = *reinterpret_cast<const short8*>(Kg + (size_t)(k0n + sr + 32) * 3072 + sc * 8);
        rv0 = *reinterpret_cast<const short8*>(Vg + (size_t)sr * T_SEQ + k0n + sc * 8);
        rv1 = *reinterpret_cast<const short8*>(Vg + (size_t)(sr + 32) * T_SEQ + k0n + sc * 8);
      }
    }

    if (kt * KVB <= qwmax) {
      const int csel = kt & 1;
      char* kcur = lds + (csel ? 8192 : 0);
      char* vcur = lds + 16384 + (csel ? 8192 : 0);
      const int ktb = kt * KVB;
      const bool notfull = (ktb + 63 > q0 + wid * 32);

      // ---- QK^T: s0 = keys[0..31], s1 = keys[32..63] (x32 q) ----
      f32x16 s0 = zero16, s1 = zero16;
      __builtin_amdgcn_s_setprio(1);
#pragma unroll
      for (int ks = 0; ks < 4; ks++) {
        short8 kf0 = *reinterpret_cast<const short8*>(kcur + rowb128 + rslot[ks]);
        short8 kf1 = *reinterpret_cast<const short8*>(kcur + 4096 + rowb128 + rslot[ks]);
        s0 = __builtin_amdgcn_mfma_f32_32x32x16_bf16(kf0, qf[ks], s0, 0, 0, 0);
        s1 = __builtin_amdgcn_mfma_f32_32x32x16_bf16(kf1, qf[ks], s1, 0, 0, 0);
      }
      __builtin_amdgcn_s_setprio(0);

      uint32_t u0[8], u1[8];
#define SMAX_KB(SV, KB, U)                                                    \
  do {                                                                        \
    _Pragma("unroll")                                                         \
    for (int r = 0; r < 16; r++) {                                            \
      float v = SV[r];                                                        \
      if (notfull) {                                                          \
        int key = ktb + (KB) * 32 + (r & 3) + 8 * (r >> 2) + hi4;             \
        if (key > qrow) v = -INFINITY;                                        \
      }                                                                       \
      float p = __builtin_amdgcn_exp2f(v);                                    \
      SV[r] = p;                                                              \
      lpart += p;                                                             \
    }                                                                         \
    _Pragma("unroll")                                                         \
    for (int jj = 0; jj < 8; jj++)                                            \
      asm("v_cvt_pk_bf16_f32 %0, %1, %2"                                      \
          : "=v"(U[jj]) : "v"(SV[2 * jj]), "v"(SV[2 * jj + 1]));              \
    asm volatile("v_permlane32_swap_b32 %0, %1" : "+v"(U[0]), "+v"(U[2]));    \
    asm volatile("v_permlane32_swap_b32 %0, %1" : "+v"(U[1]), "+v"(U[3]));    \
    asm volatile("v_permlane32_swap_b32 %0, %1" : "+v"(U[4]), "+v"(U[6]));    \
    asm volatile("v_permlane32_swap_b32 %0, %1" : "+v"(U[5]), "+v"(U[7]));    \
  } while (0)

      SMAX_KB(s0, 0, u0);
      SMAX_KB(s1, 1, u1);
#undef SMAX_KB

      union { uint32_t u[4]; short8 s; } pf;
      __builtin_amdgcn_s_setprio(1);
#pragma unroll
      for (int kv = 0; kv < 4; kv++) {
        if (kv == 0) { pf.u[0] = u0[0]; pf.u[1] = u0[1]; pf.u[2] = u0[2]; pf.u[3] = u0[3]; }
        else if (kv == 1) { pf.u[0] = u0[4]; pf.u[1] = u0[5]; pf.u[2] = u0[6]; pf.u[3] = u0[7]; }
        else if (kv == 2) { pf.u[0] = u1[0]; pf.u[1] = u1[1]; pf.u[2] = u1[2]; pf.u[3] = u1[3]; }
        else { pf.u[0] = u1[4]; pf.u[1] = u1[5]; pf.u[2] = u1[6]; pf.u[3] = u1[7]; }
        short8 vf0 = *reinterpret_cast<const short8*>(vcur + rowb128 + rslot[kv]);
        short8 vf1 = *reinterpret_cast<const short8*>(vcur + 4096 + rowb128 + rslot[kv]);
        o0 = __builtin_amdgcn_mfma_f32_32x32x16_bf16(vf0, pf.s, o0, 0, 0, 0);
        o1 = __builtin_amdgcn_mfma_f32_32x32x16_bf16(vf1, pf.s, o1, 0, 0, 0);
      }
      __builtin_amdgcn_s_setprio(0);
    }
  }

  // ---- epilogue ----
  __syncthreads();
  float ltot = lpart + __shfl_xor(lpart, 32);
  float inv = 1.0f / ltot;
  char* scrb = lds + wid * 8192;  // per-wave 8KB: [32 q][16 slots x 16B]
#pragma unroll
  for (int g = 0; g < 4; g++) {
    f32x4 w0, w1;
#pragma unroll
    for (int e = 0; e < 4; e++) { w0[e] = o0[4 * g + e] * inv; w1[e] = o1[4 * g + e] * inv; }
    int s0i = 2 * g + hi, s1i = s0i + 8;
    *reinterpret_cast<f32x4*>(scrb + l31 * 256 + ((s0i ^ (l31 & 7)) << 4)) = w0;
    *reinterpret_cast<f32x4*>(scrb + l31 * 256 + ((s1i ^ (l31 & 7)) << 4)) = w1;
  }
  asm volatile("s_waitcnt lgkmcnt(0)" ::: "memory");
  __builtin_amdgcn_sched_barrier(0);
  {
    int row = lane >> 1, half = lane & 1;
    uint16_t tmp[32];
#pragma unroll
    for (int k = 0; k < 8; k++) {
      f32x4 vv = *reinterpret_cast<const f32x4*>(
          scrb + row * 256 + (((half * 8 + k) ^ (row & 7)) << 4));
#pragma unroll
      for (int e = 0; e < 4; e++) tmp[k * 4 + e] = f2bf(vv[e]);
    }
    uint16_t* op = out + (rowbase + q0 + wid * 32 + row) * 1024 + h * 64 + half * 32;
#pragma unroll
    for (int k = 0; k < 4; k++)
      *reinterpret_cast<short8*>(op + k * 8) = *reinterpret_cast<const short8*>(tmp + k * 8);
  }
}

extern "C" void kernel_launch(void* const* d_in, const int* in_sizes, int n_in,
                              void* d_out, int out_size, void* d_ws, size_t ws_size,
                              hipStream_t stream) {
  const float* x = (const float*)d_in[0];
  const float* w_qkv = (const float*)d_in[1];
  const float* b_qkv = (const float*)d_in[2];
  const float* w_out = (const float*)d_in[3];
  const float* b_out = (const float*)d_in[4];
  float* out = (float*)d_out;

  uint8_t* ws = (uint8_t*)d_ws;
  uint16_t* x_bf  = (uint16_t*)(ws);                         // 16 MB (reused as attn_out)
  uint16_t* wqkvT = (uint16_t*)(ws + (16u << 20));           // 6 MB
  uint16_t* woutT = (uint16_t*)(ws + (22u << 20));           // 2 MB
  uint16_t* qkv   = (uint16_t*)(ws + (24u << 20));           // 48 MB
  uint16_t* vTbuf = (uint16_t*)(ws + (72u << 20));           // 16 MB
  uint16_t* attn_o = x_bf;

  k_cvt<<<8192, 256, 0, stream>>>(x, x_bf, 2097152);
  k_tc<<<dim3(96, 32), 256, 0, stream>>>(w_qkv, wqkvT, 1024, 3072);
  k_tc<<<dim3(32, 32), 256, 0, stream>>>(w_out, woutT, 1024, 1024);
  // GEMM1: 256x256 phase-split tiles -> 32*12 = 384 blocks (%8==0)
  k_gemm256p<<<384, 512, 0, stream>>>(x_bf, wqkvT, b_qkv, qkv, 8192, 3072, 1024);
  k_vt<<<dim3(64, 32), 256, 0, stream>>>(qkv, vTbuf);
  k_attn<<<1024, 256, 0, stream>>>(qkv, vTbuf, attn_o);
  // GEMM2: 128x128 tiles, 2 blk/CU (verified best for N=1024) -> 512 blocks
  k_gemm<0><<<512, 256, 0, stream>>>(attn_o, woutT, b_out, out, 8192, 1024, 1024);
}